// Round 15
// baseline (145.831 us; speedup 1.0000x reference)
//
#include <hip/hip_runtime.h>
#include <hip/hip_bf16.h>

typedef _Float16 half_t;
typedef __attribute__((ext_vector_type(8))) _Float16 half8;
typedef __attribute__((ext_vector_type(4))) _Float16 half4;
typedef __attribute__((ext_vector_type(4))) float float4v;

#define BSZ 8192
#define NT 1024     // 16 waves -> 4 waves/SIMD at grid 256 (1 block/CU)
#define ACTSTR 280  // act stride (halfs): 560B, 16B-aligned, 2-way banks max
#define XSTR 152
#define ZSTR 40

__device__ __forceinline__ float elu_fast(float v) {
    return v > 0.f ? v : (__expf(v) - 1.f);
}

// W layout (validated r14): frag-ordered 1KB blocks [e][strip][chunk][512],
// block[(quad*16+l15)*8+j] = W[n=strip*16+l15][k=chunk*32+quad*8+j].
// B path (r15): global -> REGISTER double-buffer (bcur/bnxt, rolled loop).
// Loads are lane-contiguous 16B -> 8x128B merged transactions, no LDS round-trip
// (r14 was LDS-BW-bound: 6KB/slot, 2/3 of it the B ring write+read).
template <int EXPP, int NPASS, int CH, int MT, bool ZLAST, int ACT, int DST>
__device__ __forceinline__ void layer_run(
    const half_t* sSrc, int sstr, const half_t* sZ,
    const half_t* __restrict__ W, int NS,
    const float* __restrict__ bias, int biasN, const float* sCf, float* sBias,
    half_t* sDst, float* __restrict__ gOut, int ldg,
    int row0, int strip, int mrow, int wv, int lane, int l15, int quad) {
    constexpr int TOT = NPASS * CH;
    const size_t estr = (size_t)NS * CH * 512;  // halfs per expert in layout
    const int col = strip * 16 + l15;
    float* myBias = sBias + wv * 128;

    if (quad == 0) {
#pragma unroll
        for (int e = 0; e < NPASS * EXPP; ++e)
            myBias[e * 16 + l15] = bias[e * biasN + col];
    }
    // wave-internal LDS write->read: compiler inserts lgkmcnt (no barrier needed)

    float4v acc[EXPP][MT];
    float part[MT][4];
    half8 bcur[EXPP], bnxt[EXPP];

    const half_t* wp = W + (size_t)strip * CH * 512 + lane * 8;  // lane-contiguous
#pragma unroll
    for (int e = 0; e < EXPP; ++e) bcur[e] = *(const half8*)&wp[(size_t)e * estr];
    wp += 512;
    int c_i = 1;  // chunk index of next load

    const half_t* aBase = sSrc + (mrow + l15) * sstr + quad * 8;
    const half_t* zBase = sZ + (mrow + l15) * ZSTR + quad * 8;
    int c_c = 0, h_c = 0;

#pragma unroll 1
    for (int it = 0; it < TOT; ++it) {
        if (it + 1 < TOT) {  // issue next B chunk before consuming current
#pragma unroll
            for (int e = 0; e < EXPP; ++e) bnxt[e] = *(const half8*)&wp[(size_t)e * estr];
            wp += 512;
            if (++c_i == CH) { c_i = 0; wp += EXPP * estr - (size_t)CH * 512; }
        }
        half8 a[MT];
#pragma unroll
        for (int mt = 0; mt < MT; ++mt)
            a[mt] = (ZLAST && c_c == CH - 1)
                        ? *(const half8*)&zBase[mt * 16 * ZSTR]
                        : *(const half8*)&aBase[mt * 16 * sstr + c_c * 32];
        if (c_c == 0) {
#pragma unroll
            for (int e = 0; e < EXPP; ++e)
#pragma unroll
                for (int mt = 0; mt < MT; ++mt) acc[e][mt] = (float4v){0.f, 0.f, 0.f, 0.f};
        }
#pragma unroll
        for (int e = 0; e < EXPP; ++e)
#pragma unroll
            for (int mt = 0; mt < MT; ++mt)
                acc[e][mt] = __builtin_amdgcn_mfma_f32_16x16x32_f16(a[mt], bcur[e],
                                                                    acc[e][mt], 0, 0, 0);
        if (c_c == CH - 1) {  // pass-h epilogue
            const int eoff = h_c * EXPP;
#pragma unroll
            for (int mt = 0; mt < MT; ++mt)
#pragma unroll
                for (int r = 0; r < 4; ++r) {
                    const int rl = mrow + mt * 16 + quad * 4 + r;
                    float val = 0.f;
#pragma unroll
                    for (int e = 0; e < EXPP; ++e) {
                        const float ab = acc[e][mt][r] + myBias[(eoff + e) * 16 + l15];
                        val += (EXPP * NPASS == 1) ? ab : sCf[rl * 8 + eoff + e] * ab;
                    }
                    part[mt][r] = (h_c == 0) ? val : part[mt][r] + val;
                    if (h_c == NPASS - 1) {
                        float o = part[mt][r];
                        if (DST == 0) {
                            if (ACT) o = elu_fast(o);
                            sDst[rl * ACTSTR + col] = (half_t)o;
                        } else {
                            gOut[(size_t)(row0 + rl) * ldg + col] = o;
                        }
                    }
                }
        }
        if (++c_c == CH) { c_c = 0; ++h_c; }
#pragma unroll
        for (int e = 0; e < EXPP; ++e) bcur[e] = bnxt[e];
    }
}

// Logits: N=8, wave 0 only. Wg3 in frag-block layout (strip 0, CH=8).
__device__ __forceinline__ void layer_logits(
    const half_t* sSrc, const half_t* __restrict__ W,
    const float* __restrict__ bias, float* sLog, int wv, int lane, int l15, int quad) {
    if (wv != 0) return;
    float4v acc[2] = {(float4v){0.f, 0.f, 0.f, 0.f}, (float4v){0.f, 0.f, 0.f, 0.f}};
#pragma unroll
    for (int c = 0; c < 8; ++c) {
        half8 a0 = *(const half8*)&sSrc[l15 * ACTSTR + c * 32 + quad * 8];
        half8 a1 = *(const half8*)&sSrc[(16 + l15) * ACTSTR + c * 32 + quad * 8];
        half8 b = *(const half8*)&W[c * 512 + lane * 8];
        acc[0] = __builtin_amdgcn_mfma_f32_16x16x32_f16(a0, b, acc[0], 0, 0, 0);
        acc[1] = __builtin_amdgcn_mfma_f32_16x16x32_f16(a1, b, acc[1], 0, 0, 0);
    }
    if (l15 < 8) {
        const float bvv = bias[l15];
#pragma unroll
        for (int mt = 0; mt < 2; ++mt)
#pragma unroll
            for (int r = 0; r < 4; ++r)
                sLog[(mt * 16 + quad * 4 + r) * 8 + l15] = acc[mt][r] + bvv;
    }
}

__global__ __launch_bounds__(NT) void fused_mann(
    const float* __restrict__ x, const float* __restrict__ z,
    const half_t* __restrict__ Wg0, const half_t* __restrict__ Wg1,
    const half_t* __restrict__ Wg2, const half_t* __restrict__ Wg3,
    const float* __restrict__ gb0, const float* __restrict__ gb1,
    const float* __restrict__ gb2, const float* __restrict__ gb3,
    const half_t* __restrict__ W0, const half_t* __restrict__ W1,
    const half_t* __restrict__ W2, const float* __restrict__ b0,
    const float* __restrict__ b1, const float* __restrict__ b2,
    float* __restrict__ out) {
    __shared__ __align__(16) half_t sX[32 * XSTR];
    __shared__ __align__(16) half_t sB0[32 * ACTSTR];
    __shared__ __align__(16) half_t sB1[32 * ACTSTR];
    __shared__ __align__(16) half_t sZ[32 * ZSTR];
    __shared__ float sBias[16 * 128];
    __shared__ float sLog[256];
    __shared__ float sCf[256];

    const int tid = threadIdx.x;
    const int row0 = blockIdx.x * 32;
    const int lane = tid & 63, wv = tid >> 6;  // 0..15
    const int l15 = lane & 15, quad = lane >> 4;

    for (int i = tid; i < 32 * 128; i += NT) {
        int r = i >> 7, c = i & 127;
        sX[r * XSTR + c] = (half_t)x[(size_t)(row0 + r) * 128 + c];
    }
    for (int i = tid; i < 32 * 32; i += NT) {
        int r = i >> 5, c = i & 31;
        sZ[r * ZSTR + c] = (half_t)z[(size_t)(row0 + r) * 32 + c];
    }
    __syncthreads();

    // Gating MLP (EXPP=1, 16 strips / 16 waves, MT=2)
    layer_run<1, 1, 5, 2, true, 1, 0>(sX, XSTR, sZ, Wg0, 16, gb0, 256, nullptr, sBias,
                                      sB0, nullptr, 0, row0, wv, 0, wv, lane, l15, quad);
    __syncthreads();
    layer_run<1, 1, 8, 2, false, 1, 0>(sB0, ACTSTR, sZ, Wg1, 16, gb1, 256, nullptr, sBias,
                                       sB1, nullptr, 0, row0, wv, 0, wv, lane, l15, quad);
    __syncthreads();
    layer_run<1, 1, 8, 2, false, 1, 0>(sB1, ACTSTR, sZ, Wg2, 16, gb2, 256, nullptr, sBias,
                                       sB0, nullptr, 0, row0, wv, 0, wv, lane, l15, quad);
    __syncthreads();
    layer_logits(sB0, Wg3, gb3, sLog, wv, lane, l15, quad);
    __syncthreads();
    if (tid < 32) {
        float v[8], m = -1e30f;
#pragma unroll
        for (int e = 0; e < 8; ++e) { v[e] = sLog[tid * 8 + e]; m = fmaxf(m, v[e]); }
        float sum = 0.f;
#pragma unroll
        for (int e = 0; e < 8; ++e) { v[e] = __expf(v[e] - m); sum += v[e]; }
        float inv = 1.f / sum;
#pragma unroll
        for (int e = 0; e < 8; ++e) sCf[tid * 8 + e] = v[e] * inv;
    }
    __syncthreads();
    // Expert layers: 8 experts = 4 passes x 2
    layer_run<2, 4, 5, 2, true, 1, 0>(sX, XSTR, sZ, W0, 16, b0, 256, sCf, sBias,
                                      sB1, nullptr, 0, row0, wv, 0, wv, lane, l15, quad);
    __syncthreads();
    layer_run<2, 4, 9, 2, true, 1, 0>(sB1, ACTSTR, sZ, W1, 16, b1, 256, sCf, sBias,
                                      sB0, nullptr, 0, row0, wv, 0, wv, lane, l15, quad);
    __syncthreads();
    // Final: N=128 -> 8 strips x 2 m-halves over 16 waves (MT=1)
    layer_run<2, 4, 9, 1, true, 0, 2>(sB0, ACTSTR, sZ, W2, 8, b2, 128, sCf, sBias,
                                      nullptr, out, 128, row0, wv & 7, (wv >> 3) * 16,
                                      wv, lane, l15, quad);
}

// Weight prep (validated r14): [E][K][N] fp32 -> frag-ordered fp16 1KB blocks.
struct WDesc { const float* src; half_t* dst; int K, N, Npad, blk0; };
struct WPack { WDesc d[7]; };

__global__ __launch_bounds__(256) void conv_w_all(WPack pk) {
    __shared__ float t[32][33];
    const int bid = blockIdx.x;
    int di = 0;
#pragma unroll
    for (int i = 1; i < 7; ++i)
        if (bid >= pk.d[i].blk0) di = i;
    const WDesc d = pk.d[di];
    const int NS = d.Npad >> 4, CHN = d.K >> 5;
    const int ntiles = d.Npad / 32, ktiles = CHN;
    int local = bid - d.blk0;
    const int e = local / (ktiles * ntiles);
    local %= ktiles * ntiles;
    const int k0 = (local / ntiles) * 32, n0 = (local % ntiles) * 32;
    const int tr = threadIdx.x >> 3;        // 0..31
    const int tc = (threadIdx.x & 7) * 4;   // 0,4,..,28

    float4 v = {0.f, 0.f, 0.f, 0.f};
    if (n0 + tc < d.N)
        v = *(const float4*)&d.src[((size_t)e * d.K + k0 + tr) * d.N + n0 + tc];
    t[tr][tc] = v.x; t[tr][tc + 1] = v.y; t[tr][tc + 2] = v.z; t[tr][tc + 3] = v.w;
    __syncthreads();
    half4 h;
#pragma unroll
    for (int i = 0; i < 4; ++i) h[i] = (half_t)t[tc + i][tr];
    const int n = n0 + tr;
    const size_t blk = ((size_t)e * NS + (n >> 4)) * CHN + (k0 >> 5);
    const int off = ((tc >> 3) * 16 + (n & 15)) * 8 + (tc & 7);
    *(half4*)&d.dst[blk * 512 + off] = h;
}

extern "C" void kernel_launch(void* const* d_in, const int* in_sizes, int n_in,
                              void* d_out, int out_size, void* d_ws, size_t ws_size,
                              hipStream_t stream) {
    const float* x   = (const float*)d_in[0];
    const float* z   = (const float*)d_in[1];
    const float* gw0 = (const float*)d_in[2];
    const float* gb0 = (const float*)d_in[3];
    const float* gw1 = (const float*)d_in[4];
    const float* gb1 = (const float*)d_in[5];
    const float* gw2 = (const float*)d_in[6];
    const float* gb2 = (const float*)d_in[7];
    const float* gw3 = (const float*)d_in[8];
    const float* gb3 = (const float*)d_in[9];
    const float* w0  = (const float*)d_in[10];
    const float* b0  = (const float*)d_in[11];
    const float* w1  = (const float*)d_in[12];
    const float* b1  = (const float*)d_in[13];
    const float* w2  = (const float*)d_in[14];
    const float* b2  = (const float*)d_in[15];

    char* p = (char*)d_ws;
    auto take = [&](size_t bytes) { char* r = p; p += bytes; return r; };
    half_t* Wg0 = (half_t*)take((size_t)256 * 160 * 2);
    half_t* Wg1 = (half_t*)take((size_t)256 * 256 * 2);
    half_t* Wg2 = (half_t*)take((size_t)256 * 256 * 2);
    half_t* Wg3 = (half_t*)take((size_t)32 * 256 * 2);
    half_t* W0  = (half_t*)take((size_t)8 * 256 * 160 * 2);
    half_t* W1  = (half_t*)take((size_t)8 * 256 * 288 * 2);
    half_t* W2  = (half_t*)take((size_t)8 * 128 * 288 * 2);
    float* out  = (float*)d_out;

    WPack pk;
    int blk = 0;
    auto mk = [&](int i, const float* s, half_t* dst, int K, int N, int Npad, int E) {
        pk.d[i] = WDesc{s, dst, K, N, Npad, blk};
        blk += E * (K / 32) * (Npad / 32);
    };
    mk(0, gw0, Wg0, 160, 256, 256, 1);
    mk(1, gw1, Wg1, 256, 256, 256, 1);
    mk(2, gw2, Wg2, 256, 256, 256, 1);
    mk(3, gw3, Wg3, 256, 8, 32, 1);
    mk(4, w0, W0, 160, 256, 256, 8);
    mk(5, w1, W1, 288, 256, 256, 8);
    mk(6, w2, W2, 288, 128, 128, 8);

    conv_w_all<<<dim3(blk), dim3(256), 0, stream>>>(pk);
    fused_mann<<<dim3(BSZ / 32), dim3(NT), 0, stream>>>(
        x, z, Wg0, Wg1, Wg2, Wg3, gb0, gb1, gb2, gb3,
        W0, W1, W2, b0, b1, b2, out);
}

// Round 18
// 137.532 us; speedup vs baseline: 1.0603x; 1.0603x over previous
//
#include <hip/hip_runtime.h>
#include <hip/hip_bf16.h>

typedef _Float16 half_t;
typedef __attribute__((ext_vector_type(8))) _Float16 half8;
typedef __attribute__((ext_vector_type(4))) _Float16 half4;
typedef __attribute__((ext_vector_type(4))) float float4v;

#define BSZ 8192
#define NT 1024   // 16 waves -> 4 waves/SIMD at grid 256 (1 block/CU)
#define ACTSTR 280  // act stride (halfs): 560B, 16B-aligned, 2-way banks max
#define XSTR 152    // x stride: 304B, 2-way banks
#define ZSTR 40     // z stride: 80B, 2-way banks

// ---- dynamic LDS layout (half_t units unless noted) ----
#define RING_SLOT 1024                    // 2KB slot: up to 2 experts x 1KB frag-ordered
#define RING_WAVE (3 * RING_SLOT)         // 3-slot ring per wave
#define OFF_SX   (16 * RING_WAVE)         // 49152
#define OFF_SB0  (OFF_SX + 32 * XSTR)
#define OFF_SB1  (OFF_SB0 + 32 * ACTSTR)
#define OFF_SZ   (OFF_SB1 + 32 * ACTSTR)
#define HALFS_TOTAL (OFF_SZ + 32 * ZSTR)  // 73216 halfs = 146432 B
#define OFF_BIAS_B (HALFS_TOTAL * 2)      // 8KB per-wave bias tiles
#define OFF_LOG_B  (OFF_BIAS_B + 8192)
#define OFF_CF_B   (OFF_LOG_B + 1024)
#define SMEM_BYTES (OFF_CF_B + 1024)      // 156672 <= 160K

__device__ __forceinline__ float elu_fast(float v) {
    return v > 0.f ? v : (__expf(v) - 1.f);
}

template <int N>
__device__ __forceinline__ void wait_vm() {
    if constexpr (N == 0)      asm volatile("s_waitcnt vmcnt(0)" ::: "memory");
    else if constexpr (N == 1) asm volatile("s_waitcnt vmcnt(1)" ::: "memory");
    else if constexpr (N == 2) asm volatile("s_waitcnt vmcnt(2)" ::: "memory");
    else                       asm volatile("s_waitcnt vmcnt(4)" ::: "memory");
}

// async global->LDS DMA, 16B/lane; lds base wave-uniform, HW writes +lane*16B.
__device__ __forceinline__ void lds_dma16(half_t* lds, const half_t* g) {
    __builtin_amdgcn_global_load_lds(
        (const __attribute__((address_space(1))) void*)g,
        (__attribute__((address_space(3))) void*)lds, 16, 0, 0);
}

// W layout (validated r14): frag-ordered 1KB blocks [e][strip][chunk][512 halfs],
// block[(quad*16+l15)*8+j] = W[n=strip*16+l15][k=chunk*32+quad*8+j]. A wave's
// DMA src = base + lane*16B -> contiguous 1KB, 8x128B merged transactions.
// B streams through a per-wave 3-slot LDS ring, drained with manual vmcnt(N>0).
// *** The ring loop MUST stay `#pragma unroll 1` *** — measured twice (r16 hand
// unroll, r17 `unroll 3`): any unrolling lets the scheduler reorder the DMA
// issues across the asm waits, breaking the vmcnt baseline (absmax ~1e-2).
template <int EXPP, int NPASS, int CH, int MT, bool ZLAST, int ACT, int DST>
__device__ __forceinline__ void layer_run(
    half_t* sm, const half_t* sSrc, int sstr,
    const half_t* __restrict__ W, int NS,
    const float* __restrict__ bias, int biasN, const float* sCf, float* sBias,
    half_t* sDst, float* __restrict__ gOut, int ldg,
    int row0, int strip, int mrow, int wv, int lane, int l15, int quad) {
    constexpr int TOT = NPASS * CH;
    const size_t estr = (size_t)NS * CH * 512;  // halfs per expert in layout
    const int col = strip * 16 + l15;
    half_t* ring = sm + wv * RING_WAVE;
    const half_t* sZ = sm + OFF_SZ;
    float* myBias = sBias + wv * 128;

    if (quad == 0) {
#pragma unroll
        for (int e = 0; e < NPASS * EXPP; ++e)
            myBias[e * 16 + l15] = bias[e * biasN + col];
    }
    wait_vm<0>();  // drain bias loads -> clean vmcnt baseline for the ring

    float4v acc[EXPP][MT];
    float part[MT][4];

    const half_t* wp = W + (size_t)strip * CH * 512 + lane * 8;  // lane-ordered
    int s_i = 0, c_i = 0;
    auto issue = [&]() {
        half_t* slot = ring + s_i * RING_SLOT;
#pragma unroll
        for (int e = 0; e < EXPP; ++e) lds_dma16(slot + e * 512, wp + (size_t)e * estr);
        s_i = (s_i == 2) ? 0 : s_i + 1;
        wp += 512;
        if (++c_i == CH) { c_i = 0; wp += EXPP * estr - CH * 512; }
    };

    const half_t* aBase = sSrc + (mrow + l15) * sstr + quad * 8;
    const half_t* zBase = sZ + (mrow + l15) * ZSTR + quad * 8;
    int s_c = 0, c_c = 0, h_c = 0;
    auto body = [&]() {
        half8 a[MT];
#pragma unroll
        for (int mt = 0; mt < MT; ++mt)
            a[mt] = (ZLAST && c_c == CH - 1)
                        ? *(const half8*)&zBase[mt * 16 * ZSTR]
                        : *(const half8*)&aBase[mt * 16 * sstr + c_c * 32];
        if (c_c == 0) {
#pragma unroll
            for (int e = 0; e < EXPP; ++e)
#pragma unroll
                for (int mt = 0; mt < MT; ++mt) acc[e][mt] = (float4v){0.f, 0.f, 0.f, 0.f};
        }
        const half_t* slot = ring + s_c * RING_SLOT + lane * 8;
#pragma unroll
        for (int e = 0; e < EXPP; ++e) {
            half8 b = *(const half8*)&slot[e * 512];
#pragma unroll
            for (int mt = 0; mt < MT; ++mt)
                acc[e][mt] = __builtin_amdgcn_mfma_f32_16x16x32_f16(a[mt], b, acc[e][mt], 0, 0, 0);
        }
        if (c_c == CH - 1) {  // pass-h epilogue
            const int eoff = h_c * EXPP;
#pragma unroll
            for (int mt = 0; mt < MT; ++mt)
#pragma unroll
                for (int r = 0; r < 4; ++r) {
                    const int rl = mrow + mt * 16 + quad * 4 + r;
                    float val = 0.f;
#pragma unroll
                    for (int e = 0; e < EXPP; ++e) {
                        const float ab = acc[e][mt][r] + myBias[(eoff + e) * 16 + l15];
                        val += (EXPP * NPASS == 1) ? ab : sCf[rl * 8 + eoff + e] * ab;
                    }
                    part[mt][r] = (h_c == 0) ? val : part[mt][r] + val;
                    if (h_c == NPASS - 1) {
                        float o = part[mt][r];
                        if (DST == 0) {
                            if (ACT) o = elu_fast(o);
                            sDst[rl * ACTSTR + col] = (half_t)o;
                        } else {
                            gOut[(size_t)(row0 + rl) * ldg + col] = o;
                        }
                    }
                }
        }
        s_c = (s_c == 2) ? 0 : s_c + 1;
        if (++c_c == CH) { c_c = 0; ++h_c; }
    };

    issue();
    issue();
#pragma unroll 1
    for (int it = 0; it < TOT - 2; ++it) {
        issue();                 // keep 3 slots in flight
        wait_vm<2 * EXPP>();     // drain only the oldest slot — never vmcnt(0) mid-loop
        body();
    }
    wait_vm<EXPP>();
    body();
    wait_vm<0>();
    body();
}

// Logits: N=8, wave 0 only. Wg3 in frag-block layout (NS=2, CH=8), strip 0.
__device__ __forceinline__ void layer_logits(
    const half_t* sSrc, const half_t* __restrict__ W,
    const float* __restrict__ bias, float* sLog, int wv, int lane, int l15, int quad) {
    if (wv != 0) return;
    float4v acc[2] = {(float4v){0.f, 0.f, 0.f, 0.f}, (float4v){0.f, 0.f, 0.f, 0.f}};
#pragma unroll
    for (int c = 0; c < 8; ++c) {
        half8 a0 = *(const half8*)&sSrc[l15 * ACTSTR + c * 32 + quad * 8];
        half8 a1 = *(const half8*)&sSrc[(16 + l15) * ACTSTR + c * 32 + quad * 8];
        half8 b = *(const half8*)&W[c * 512 + lane * 8];
        acc[0] = __builtin_amdgcn_mfma_f32_16x16x32_f16(a0, b, acc[0], 0, 0, 0);
        acc[1] = __builtin_amdgcn_mfma_f32_16x16x32_f16(a1, b, acc[1], 0, 0, 0);
    }
    if (l15 < 8) {
        const float bvv = bias[l15];
#pragma unroll
        for (int mt = 0; mt < 2; ++mt)
#pragma unroll
            for (int r = 0; r < 4; ++r)
                sLog[(mt * 16 + quad * 4 + r) * 8 + l15] = acc[mt][r] + bvv;
    }
}

__global__ __launch_bounds__(NT) void fused_mann(
    const float* __restrict__ x, const float* __restrict__ z,
    const half_t* __restrict__ Wg0, const half_t* __restrict__ Wg1,
    const half_t* __restrict__ Wg2, const half_t* __restrict__ Wg3,
    const float* __restrict__ gb0, const float* __restrict__ gb1,
    const float* __restrict__ gb2, const float* __restrict__ gb3,
    const half_t* __restrict__ W0, const half_t* __restrict__ W1,
    const half_t* __restrict__ W2, const float* __restrict__ b0,
    const float* __restrict__ b1, const float* __restrict__ b2,
    float* __restrict__ out) {
    extern __shared__ __align__(16) char dynsm[];
    half_t* sm = (half_t*)dynsm;
    half_t* sX = sm + OFF_SX;
    half_t* sB0 = sm + OFF_SB0;
    half_t* sB1 = sm + OFF_SB1;
    half_t* sZ = sm + OFF_SZ;
    float* sBias = (float*)(dynsm + OFF_BIAS_B);
    float* sLog = (float*)(dynsm + OFF_LOG_B);
    float* sCf = (float*)(dynsm + OFF_CF_B);

    const int tid = threadIdx.x;
    const int row0 = blockIdx.x * 32;
    const int lane = tid & 63, wv = tid >> 6;  // 0..15
    const int l15 = lane & 15, quad = lane >> 4;

    for (int i = tid; i < 32 * 128; i += NT) {
        int r = i >> 7, c = i & 127;
        sX[r * XSTR + c] = (half_t)x[(size_t)(row0 + r) * 128 + c];
    }
    for (int i = tid; i < 32 * 32; i += NT) {
        int r = i >> 5, c = i & 31;
        sZ[r * ZSTR + c] = (half_t)z[(size_t)(row0 + r) * 32 + c];
    }
    __syncthreads();

    // Gating MLP (EXPP=1, 16 strips / 16 waves, MT=2)
    layer_run<1, 1, 5, 2, true, 1, 0>(sm, sX, XSTR, Wg0, 16, gb0, 256, nullptr, sBias,
                                      sB0, nullptr, 0, row0, wv, 0, wv, lane, l15, quad);
    __syncthreads();
    layer_run<1, 1, 8, 2, false, 1, 0>(sm, sB0, ACTSTR, Wg1, 16, gb1, 256, nullptr, sBias,
                                       sB1, nullptr, 0, row0, wv, 0, wv, lane, l15, quad);
    __syncthreads();
    layer_run<1, 1, 8, 2, false, 1, 0>(sm, sB1, ACTSTR, Wg2, 16, gb2, 256, nullptr, sBias,
                                       sB0, nullptr, 0, row0, wv, 0, wv, lane, l15, quad);
    __syncthreads();
    layer_logits(sB0, Wg3, gb3, sLog, wv, lane, l15, quad);
    __syncthreads();
    if (tid < 32) {
        float v[8], m = -1e30f;
#pragma unroll
        for (int e = 0; e < 8; ++e) { v[e] = sLog[tid * 8 + e]; m = fmaxf(m, v[e]); }
        float sum = 0.f;
#pragma unroll
        for (int e = 0; e < 8; ++e) { v[e] = __expf(v[e] - m); sum += v[e]; }
        float inv = 1.f / sum;
#pragma unroll
        for (int e = 0; e < 8; ++e) sCf[tid * 8 + e] = v[e] * inv;
    }
    __syncthreads();
    // Expert layers: 8 experts = 4 passes x 2
    layer_run<2, 4, 5, 2, true, 1, 0>(sm, sX, XSTR, W0, 16, b0, 256, sCf, sBias,
                                      sB1, nullptr, 0, row0, wv, 0, wv, lane, l15, quad);
    __syncthreads();
    layer_run<2, 4, 9, 2, true, 1, 0>(sm, sB1, ACTSTR, W1, 16, b1, 256, sCf, sBias,
                                      sB0, nullptr, 0, row0, wv, 0, wv, lane, l15, quad);
    __syncthreads();
    // Final: N=128 -> 8 strips x 2 m-halves over 16 waves (MT=1)
    layer_run<2, 4, 9, 1, true, 0, 2>(sm, sB0, ACTSTR, W2, 8, b2, 128, sCf, sBias,
                                      nullptr, out, 128, row0, wv & 7, (wv >> 3) * 16,
                                      wv, lane, l15, quad);
}

// Weight prep (validated r14): [E][K][N] fp32 -> frag-ordered fp16 1KB blocks
// dst[((e*NS + n/16)*CHN + k/32)*512 + ((k%32/8)*16 + n%16)*8 + k%8], zero-pad n>=N.
struct WDesc { const float* src; half_t* dst; int K, N, Npad, blk0; };
struct WPack { WDesc d[7]; };

__global__ __launch_bounds__(256) void conv_w_all(WPack pk) {
    __shared__ float t[32][33];
    const int bid = blockIdx.x;
    int di = 0;
#pragma unroll
    for (int i = 1; i < 7; ++i)
        if (bid >= pk.d[i].blk0) di = i;
    const WDesc d = pk.d[di];
    const int NS = d.Npad >> 4, CHN = d.K >> 5;
    const int ntiles = d.Npad / 32, ktiles = CHN;
    int local = bid - d.blk0;
    const int e = local / (ktiles * ntiles);
    local %= ktiles * ntiles;
    const int k0 = (local / ntiles) * 32, n0 = (local % ntiles) * 32;
    const int tr = threadIdx.x >> 3;        // 0..31
    const int tc = (threadIdx.x & 7) * 4;   // 0,4,..,28

    float4 v = {0.f, 0.f, 0.f, 0.f};
    if (n0 + tc < d.N)
        v = *(const float4*)&d.src[((size_t)e * d.K + k0 + tr) * d.N + n0 + tc];
    t[tr][tc] = v.x; t[tr][tc + 1] = v.y; t[tr][tc + 2] = v.z; t[tr][tc + 3] = v.w;
    __syncthreads();
    half4 h;
#pragma unroll
    for (int i = 0; i < 4; ++i) h[i] = (half_t)t[tc + i][tr];
    const int n = n0 + tr;
    const size_t blk = ((size_t)e * NS + (n >> 4)) * CHN + (k0 >> 5);
    const int off = ((tc >> 3) * 16 + (n & 15)) * 8 + (tc & 7);
    *(half4*)&d.dst[blk * 512 + off] = h;
}

extern "C" void kernel_launch(void* const* d_in, const int* in_sizes, int n_in,
                              void* d_out, int out_size, void* d_ws, size_t ws_size,
                              hipStream_t stream) {
    const float* x   = (const float*)d_in[0];
    const float* z   = (const float*)d_in[1];
    const float* gw0 = (const float*)d_in[2];
    const float* gb0 = (const float*)d_in[3];
    const float* gw1 = (const float*)d_in[4];
    const float* gb1 = (const float*)d_in[5];
    const float* gw2 = (const float*)d_in[6];
    const float* gb2 = (const float*)d_in[7];
    const float* gw3 = (const float*)d_in[8];
    const float* gb3 = (const float*)d_in[9];
    const float* w0  = (const float*)d_in[10];
    const float* b0  = (const float*)d_in[11];
    const float* w1  = (const float*)d_in[12];
    const float* b1  = (const float*)d_in[13];
    const float* w2  = (const float*)d_in[14];
    const float* b2  = (const float*)d_in[15];

    char* p = (char*)d_ws;
    auto take = [&](size_t bytes) { char* r = p; p += bytes; return r; };
    half_t* Wg0 = (half_t*)take((size_t)256 * 160 * 2);
    half_t* Wg1 = (half_t*)take((size_t)256 * 256 * 2);
    half_t* Wg2 = (half_t*)take((size_t)256 * 256 * 2);
    half_t* Wg3 = (half_t*)take((size_t)32 * 256 * 2);
    half_t* W0  = (half_t*)take((size_t)8 * 256 * 160 * 2);
    half_t* W1  = (half_t*)take((size_t)8 * 256 * 288 * 2);
    half_t* W2  = (half_t*)take((size_t)8 * 128 * 288 * 2);
    float* out  = (float*)d_out;

    WPack pk;
    int blk = 0;
    auto mk = [&](int i, const float* s, half_t* dst, int K, int N, int Npad, int E) {
        pk.d[i] = WDesc{s, dst, K, N, Npad, blk};
        blk += E * (K / 32) * (Npad / 32);
    };
    mk(0, gw0, Wg0, 160, 256, 256, 1);
    mk(1, gw1, Wg1, 256, 256, 256, 1);
    mk(2, gw2, Wg2, 256, 256, 256, 1);
    mk(3, gw3, Wg3, 256, 8, 32, 1);
    mk(4, w0, W0, 160, 256, 256, 8);
    mk(5, w1, W1, 288, 256, 256, 8);
    mk(6, w2, W2, 288, 128, 128, 8);

    hipFuncSetAttribute((const void*)fused_mann,
                        hipFuncAttributeMaxDynamicSharedMemorySize, SMEM_BYTES);

    conv_w_all<<<dim3(blk), dim3(256), 0, stream>>>(pk);
    fused_mann<<<dim3(BSZ / 32), dim3(NT), SMEM_BYTES, stream>>>(
        x, z, Wg0, Wg1, Wg2, Wg3, gb0, gb1, gb2, gb3,
        W0, W1, W2, b0, b1, b2, out);
}